// Round 14
// baseline (135.502 us; speedup 1.0000x reference)
//
#include <hip/hip_runtime.h>
#include <math.h>

#define BB_ 4096      // batch
#define DD_ 64        // emb dim
#define NI_ 10000     // items

// BIG kernel: EXACTLY ONE dispatch round: 1024 blocks = 4 blocks/CU @ 40KB LDS.
// Blocks 0-255 GRU, 256-767 attn, then ALL blocks stream matvec rows with a
// STATIC balanced split (compute waves 2 rows; pure waves 4 or 3 rows).
#define GRU_BLOCKS  256                   // 16 rows/block
#define ATT_BLOCKS  512                   // 8 rows/block
#define BIG_BLOCKS  1024

#define LDSF 10016                        // 40064 B; 4 blocks/CU = 160256 <= 163840

#define S1_BLOCKS 40  // top-5 stage-1 blocks (250 items each)

typedef unsigned long long u64;
typedef float v4f __attribute__((ext_vector_type(4)));

// ---------------- threefry2x32 (JAX PRNG, key=42, partitionable path) ----------------
__device__ inline unsigned rotl32(unsigned x, unsigned r){ return (x<<r)|(x>>(32u-r)); }

__device__ inline float jax_uniform_key42(int i){
  const unsigned k0 = 0u, k1 = 42u;
  const unsigned ks2 = 0x1BD11BDAu ^ k0 ^ k1;
  unsigned x0 = 0u, x1 = (unsigned)i;               // counter (hi, lo) = (0, i)
  unsigned ks[3] = {k0, k1, ks2};
  x0 += ks[0]; x1 += ks[1];
  const unsigned R0[4] = {13u,15u,26u,6u};
  const unsigned R1[4] = {17u,29u,16u,24u};
  #pragma unroll
  for (int it = 0; it < 5; ++it){
    const unsigned* R = (it & 1) ? R1 : R0;
    #pragma unroll
    for (int j = 0; j < 4; ++j){ x0 += x1; x1 = rotl32(x1, R[j]); x1 ^= x0; }
    x0 += ks[(it+1)%3];
    x1 += ks[(it+2)%3] + (unsigned)(it+1);
  }
  unsigned bits = x0 ^ x1;                          // partitionable 32-bit tail
  unsigned f = (bits >> 9) | 0x3F800000u;
  return __uint_as_float(f) - 1.0f;
}

// ---------------- kernel 0: histogram of v (float counts) ----------------
__global__ __launch_bounds__(1024) void hist_kernel(
    const int* __restrict__ v, float* __restrict__ w_out)
{
  __shared__ float wl[NI_];
  const int tid = threadIdx.x;
  for (int i = tid; i < NI_; i += 1024) wl[i] = 0.0f;
  __syncthreads();
  for (int i = tid; i < BB_; i += 1024) atomicAdd(&wl[v[i]], 1.0f);
  __syncthreads();
  for (int i = tid; i < NI_; i += 1024) w_out[i] = wl[i];
}

__device__ inline float dot4v(v4f a, v4f b){
  return a.x*b.x + a.y*b.y + a.z*b.z + a.w*b.w;
}

// ---------------- BIG fused kernel: GRU | attn roles, then static matvec rows ----------------
__global__ __launch_bounds__(256, 4) void big_kernel(
    const int* __restrict__ u, const int* __restrict__ v,
    const float* __restrict__ delta_t, const float* __restrict__ edge_feat,
    const float* __restrict__ w_in, const float* __restrict__ returns,
    const float* __restrict__ cov, float* __restrict__ combined,
    const float* __restrict__ user_emb, const float* __restrict__ item_emb,
    const float* __restrict__ mem,
    const float* __restrict__ w_ih, const float* __restrict__ w_hh,
    const float* __restrict__ b_ih, const float* __restrict__ b_hh,
    const float* __restrict__ in_w, const float* __restrict__ in_b,
    const float* __restrict__ out_w, const float* __restrict__ out_b,
    float* __restrict__ h_new_out, float* __restrict__ z_out)
{
  __shared__ __align__(16) float S[LDSF];
  const int tid  = threadIdx.x;
  const int lane = tid & 63, wid = tid >> 6;
  const int bid  = blockIdx.x;

  if (bid < GRU_BLOCKS) {
    // ======== GRU: unified 194-col stream, 7 chunks of <=32 cols ========
    float* T  = S;                                    // [cc][o], stride 193, cc<32
    float* BI = S + 6176;                             // 192
    float* BH = S + 6368;                             // 192
    const int rowbase = bid * 16 + wid * 4;

    if (tid < 192) { BI[tid] = b_ih[tid]; BH[tid] = b_hh[tid]; }

    float u_d[4], v_d[4], h_d[4], dt[4], ef[4];
    int bb[4];
    #pragma unroll
    for (int rr = 0; rr < 4; ++rr) {
      int b = rowbase + rr; bb[rr] = b;
      int uu = u[b], vv = v[b];
      u_d[rr] = user_emb[uu*64 + lane];
      v_d[rr] = item_emb[vv*64 + lane];
      h_d[rr] = mem[uu*64 + lane];
      dt[rr]  = delta_t[b];
      ef[rr]  = edge_feat[b];
    }

    float accR[4], accZ[4], accN[4], hN[4];
    bool init = false;

    for (int c = 0; c < 194; c += 32) {
      const int ncols = (194 - c < 32) ? (194 - c) : 32;
      __syncthreads();
      for (int idx = tid; idx < ncols*192; idx += 256) {
        int cc = idx / 192, o = idx - cc*192;
        int col = c + cc;
        T[cc*193 + o] = (col < 130) ? w_ih[o*130 + col] : w_hh[o*64 + (col-130)];
      }
      __syncthreads();

      if (!init) {
        init = true;
        float biR = BI[lane], biZ = BI[64+lane], biN = BI[128+lane];
        float bhR = BH[lane], bhZ = BH[64+lane], bhN = BH[128+lane];
        #pragma unroll
        for (int rr = 0; rr < 4; ++rr) { accR[rr]=biR+bhR; accZ[rr]=biZ+bhZ; accN[rr]=biN; hN[rr]=bhN; }
      }

      for (int cc = 0; cc < ncols; ++cc) {
        const int col = c + cc;
        float wR = T[cc*193 + lane], wZ = T[cc*193 + 64 + lane], wN = T[cc*193 + 128 + lane];
        if (col < 130) {
          #pragma unroll
          for (int rr = 0; rr < 4; ++rr) {
            float m = (col < 64)  ? __shfl(u_d[rr], col)
                    : (col < 128) ? __shfl(v_d[rr], col-64)
                    : (col == 128) ? dt[rr] : ef[rr];
            accR[rr] = fmaf(wR, m, accR[rr]); accZ[rr] = fmaf(wZ, m, accZ[rr]); accN[rr] = fmaf(wN, m, accN[rr]);
          }
        } else {
          #pragma unroll
          for (int rr = 0; rr < 4; ++rr) {
            float m = __shfl(h_d[rr], col-130);
            accR[rr] = fmaf(wR, m, accR[rr]); accZ[rr] = fmaf(wZ, m, accZ[rr]); hN[rr] = fmaf(wN, m, hN[rr]);
          }
        }
      }
    }

    #pragma unroll
    for (int rr = 0; rr < 4; ++rr) {
      float r = 1.0f / (1.0f + expf(-accR[rr]));
      float z = 1.0f / (1.0f + expf(-accZ[rr]));
      float n = tanhf(accN[rr] + r * hN[rr]);
      float hn = (1.0f - z) * n + z * h_d[rr];
      h_new_out[bb[rr]*64 + lane] = hn;
    }
  } else if (bid < GRU_BLOCKS + ATT_BLOCKS) {
    // ======== attn: 4 staged phases sharing one 64x65 buffer ========
    float* C    = S;                                  // 4160
    float* BIN  = S + 4160;                           // 192
    float* BOUT = S + 4352;                           // 64
    const int abid = bid - GRU_BLOCKS;
    const int rowbase = abid * 8 + wid * 2;

    if (tid < 192) BIN[tid] = in_b[tid];
    if (tid < 64)  BOUT[tid] = out_b[tid];

    float u_d[2], x1_d[2];
    int bb[2];
    #pragma unroll
    for (int rr = 0; rr < 2; ++rr) {
      int b = rowbase + rr; bb[rr] = b;
      int uu = u[b], vv = v[b];
      float ef = edge_feat[b];
      u_d[rr]  = user_emb[uu*64 + lane];
      x1_d[rr] = item_emb[vv*64 + lane] + ef;
    }

    float q0[2], k0[2], k1[2], v0[2], v1[2];

    // phase 0: q (token 0 only)
    for (int idx = tid; idx < 4096; idx += 256) {
      int o = idx >> 6, j = idx & 63;
      C[j*65 + o] = in_w[o*64 + j];
    }
    __syncthreads();
    {
      float bq = BIN[lane];
      #pragma unroll
      for (int rr = 0; rr < 2; ++rr) q0[rr] = bq;
      for (int j = 0; j < 64; ++j) {
        float wq = C[j*65 + lane];
        #pragma unroll
        for (int rr = 0; rr < 2; ++rr) q0[rr] = fmaf(wq, __shfl(u_d[rr], j), q0[rr]);
      }
    }
    __syncthreads();

    // phase 1: k (both tokens)
    for (int idx = tid; idx < 4096; idx += 256) {
      int o = idx >> 6, j = idx & 63;
      C[j*65 + o] = in_w[(64+o)*64 + j];
    }
    __syncthreads();
    {
      float bk = BIN[64+lane];
      #pragma unroll
      for (int rr = 0; rr < 2; ++rr) { k0[rr] = bk; k1[rr] = bk; }
      for (int j = 0; j < 64; ++j) {
        float wk = C[j*65 + lane];
        #pragma unroll
        for (int rr = 0; rr < 2; ++rr) {
          k0[rr] = fmaf(wk, __shfl(u_d[rr], j),  k0[rr]);
          k1[rr] = fmaf(wk, __shfl(x1_d[rr], j), k1[rr]);
        }
      }
    }
    __syncthreads();

    // phase 2: v (both tokens)
    for (int idx = tid; idx < 4096; idx += 256) {
      int o = idx >> 6, j = idx & 63;
      C[j*65 + o] = in_w[(128+o)*64 + j];
    }
    __syncthreads();
    {
      float bv = BIN[128+lane];
      #pragma unroll
      for (int rr = 0; rr < 2; ++rr) { v0[rr] = bv; v1[rr] = bv; }
      for (int j = 0; j < 64; ++j) {
        float wv = C[j*65 + lane];
        #pragma unroll
        for (int rr = 0; rr < 2; ++rr) {
          v0[rr] = fmaf(wv, __shfl(u_d[rr], j),  v0[rr]);
          v1[rr] = fmaf(wv, __shfl(x1_d[rr], j), v1[rr]);
        }
      }
    }
    __syncthreads();

    // phase 3: out_w into the same buffer
    for (int idx = tid; idx < 4096; idx += 256) {
      int k = idx >> 6, j = idx & 63;
      C[j*65 + k] = out_w[idx];                       // C[j][k] = W_out[k][j]
    }
    __syncthreads();

    #pragma unroll
    for (int rr = 0; rr < 2; ++rr) {
      float p0 = q0[rr]*k0[rr], p1 = q0[rr]*k1[rr];
      #pragma unroll
      for (int off = 1; off < 16; off <<= 1) { p0 += __shfl_xor(p0, off); p1 += __shfl_xor(p1, off); }
      float s0 = p0 * 0.25f, s1 = p1 * 0.25f;
      float m  = fmaxf(s0, s1);
      float e0 = expf(s0 - m), e1 = expf(s1 - m);
      float inv = 1.0f / (e0 + e1);
      float o_d = (e0 * v0[rr] + e1 * v1[rr]) * inv;
      float zacc = BOUT[lane];
      for (int j = 0; j < 64; ++j)
        zacc = fmaf(C[j*65 + lane], __shfl(o_d, j), zacc);
      z_out[bb[rr]*64 + lane] = zacc;
    }
  }

  // ======== matvec phase: ALL blocks; static balanced row split ========
  __syncthreads();                                     // role code done with S
  {
    const float4* src = (const float4*)w_in;
    float4* dst = (float4*)S;
    for (int i = tid; i < NI_/4; i += 256) dst[i] = src[i];
  }
  __syncthreads();
  const v4f* w4 = (const v4f*)S;

  // Wave W (= bid*4+wid): compute waves (W<3072) take 2 rows (rows 0..6143);
  // pure waves: idx<784 -> 4 rows, else 3 rows (rows 6144..9999).
  const int W = bid * 4 + wid;
  int row0, nrows;
  if (W < 3072) { row0 = W * 2; nrows = 2; }
  else {
    const int idx = W - 3072;
    if (idx < 784) { row0 = 6144 + idx * 4; nrows = 4; }
    else           { row0 = 9280 + (idx - 784) * 3; nrows = 3; }
  }

  for (int rr = 0; rr < nrows; ++rr) {
    const int row = row0 + rr;
    const v4f* r4 = (const v4f*)(cov + (size_t)row * NI_);

    float a0 = 0.0f, a1 = 0.0f, a2 = 0.0f, a3 = 0.0f;
    int k = lane;
    #pragma unroll 1
    for (int it = 0; it < 9; ++it, k += 256) {
      v4f c0 = __builtin_nontemporal_load(&r4[k]);
      v4f c1 = __builtin_nontemporal_load(&r4[k+64]);
      v4f c2 = __builtin_nontemporal_load(&r4[k+128]);
      v4f c3 = __builtin_nontemporal_load(&r4[k+192]);
      v4f w0 = w4[k], w1 = w4[k+64], w2 = w4[k+128], w3 = w4[k+192];
      a0 += dot4v(c0, w0);
      a1 += dot4v(c1, w1);
      a2 += dot4v(c2, w2);
      a3 += dot4v(c3, w3);
    }
    #pragma unroll 1
    for (int it = 0; it < 3; ++it, k += 64) {
      v4f c0 = __builtin_nontemporal_load(&r4[k]);
      a0 += dot4v(c0, w4[k]);
    }
    if (lane < 4) {
      v4f c0 = __builtin_nontemporal_load(&r4[2496 + lane]);
      a1 += dot4v(c0, w4[2496 + lane]);
    }
    float acc = (a0 + a1) + (a2 + a3);
    #pragma unroll
    for (int off = 32; off > 0; off >>= 1) acc += __shfl_xor(acc, off);

    if (lane == 0) {
      float cov_val = acc * (1.0f / (float)BB_);
      float mv = returns[row] - 0.5f * cov_val;       // GAMMA = 1
      float pref = jax_uniform_key42(row);
      combined[row] = 0.5f * mv + 0.5f * pref;        // LAM = 0.5
    }
  }
}

// ---------------- top-5 helpers ----------------
__device__ inline u64 shfl_down_u64(u64 x, int off){
  unsigned lo = (unsigned)(x & 0xFFFFFFFFull), hi = (unsigned)(x >> 32);
  lo = __shfl_down(lo, off); hi = __shfl_down(hi, off);
  return ((u64)hi << 32) | (u64)lo;
}

__device__ inline u64 make_key(float val, int i){
  unsigned u = __float_as_uint(val);
  u ^= (u >> 31) ? 0xFFFFFFFFu : 0x80000000u;       // order-preserving float->uint
  return ((u64)u << 32) | (u64)(0xFFFFFFFFu - (unsigned)i); // tie: lower idx wins
}

// ---------------- kernel 2a: per-slice top-5 (40 blocks, 250 items each) ----------------
__global__ __launch_bounds__(256) void top5_stage1(
    const float* __restrict__ combined, u64* __restrict__ keys_out)
{
  __shared__ u64 redL[4];
  __shared__ u64 sel;
  const int tid = threadIdx.x, lane = tid & 63, wid = tid >> 6;
  const int i = blockIdx.x * 250 + tid;

  u64 key = 0ull;
  if (tid < 250 && i < NI_) key = make_key(combined[i], i);

  for (int r = 0; r < 5; ++r) {
    u64 best = key;
    #pragma unroll
    for (int off = 32; off > 0; off >>= 1) {
      u64 o = shfl_down_u64(best, off);
      if (o > best) best = o;
    }
    if (lane == 0) redL[wid] = best;
    __syncthreads();
    if (tid == 0) {
      u64 b = redL[0];
      for (int wv = 1; wv < 4; ++wv) if (redL[wv] > b) b = redL[wv];
      sel = b;
      keys_out[blockIdx.x * 5 + r] = b;
    }
    __syncthreads();
    if (key == sel) key = 0ull;
  }
}

// ---------------- kernel 2b: 16 blocks; each reduces 200 keys + emits 256 rows ----------------
__global__ __launch_bounds__(256) void top5_stage2(
    const u64* __restrict__ keys_in, const int* __restrict__ v,
    float* __restrict__ pos_out, float* __restrict__ neg_out)
{
  __shared__ u64 redL[4];
  __shared__ u64 sel;
  __shared__ int chosen[5];
  const int tid = threadIdx.x, lane = tid & 63, wid = tid >> 6;

  u64 key = (tid < 5 * S1_BLOCKS) ? keys_in[tid] : 0ull;

  for (int r = 0; r < 5; ++r) {
    u64 best = key;
    #pragma unroll
    for (int off = 32; off > 0; off >>= 1) {
      u64 o = shfl_down_u64(best, off);
      if (o > best) best = o;
    }
    if (lane == 0) redL[wid] = best;
    __syncthreads();
    if (tid == 0) {
      u64 b = redL[0];
      for (int wv = 1; wv < 4; ++wv) if (redL[wv] > b) b = redL[wv];
      sel = b;
      chosen[r] = (int)(0xFFFFFFFFu - (unsigned)(b & 0xFFFFFFFFull));
    }
    __syncthreads();
    if (key == sel) key = 0ull;
  }

  const int b = blockIdx.x * 256 + tid;   // 16 blocks x 256 = 4096 rows
  int vb = v[b];
  int f[4]; int n = 0;
  #pragma unroll
  for (int c = 0; c < 5; ++c) { if (n < 4 && chosen[c] != vb) f[n++] = chosen[c]; }
  pos_out[b]       = (float)f[0];
  neg_out[b*3 + 0] = (float)f[1];
  neg_out[b*3 + 1] = (float)f[2];
  neg_out[b*3 + 2] = (float)f[3];
}

// ---------------- launch ----------------
extern "C" void kernel_launch(void* const* d_in, const int* in_sizes, int n_in,
                              void* d_out, int out_size, void* d_ws, size_t ws_size,
                              hipStream_t stream)
{
  const int*   u        = (const int*)d_in[0];
  const int*   v        = (const int*)d_in[1];
  /* t = d_in[2] unused */
  const float* delta_t  = (const float*)d_in[3];
  const float* edge_f   = (const float*)d_in[4];
  const float* returns  = (const float*)d_in[5];
  const float* cov      = (const float*)d_in[6];
  const float* user_emb = (const float*)d_in[7];
  const float* item_emb = (const float*)d_in[8];
  const float* mem      = (const float*)d_in[9];
  const float* w_ih     = (const float*)d_in[10];
  const float* w_hh     = (const float*)d_in[11];
  const float* b_ih     = (const float*)d_in[12];
  const float* b_hh     = (const float*)d_in[13];
  const float* in_w     = (const float*)d_in[14];
  const float* in_b     = (const float*)d_in[15];
  const float* out_w    = (const float*)d_in[16];
  const float* out_b    = (const float*)d_in[17];

  float* out     = (float*)d_out;
  float* z_out   = out;                    // B*D
  float* h_out   = out + BB_*DD_;          // B*D
  float* pos_out = out + 2*BB_*DD_;        // B
  float* neg_out = out + 2*BB_*DD_ + BB_;  // B*3

  float* ws        = (float*)d_ws;
  float* w_hist    = ws;                   // NI_ floats (16B-aligned)
  float* combined  = ws + 10240;           // NI_ floats
  u64*   keys      = (u64*)(ws + 20480);   // S1_BLOCKS*5 u64

  hipLaunchKernelGGL(hist_kernel, dim3(1), dim3(1024), 0, stream, v, w_hist);
  hipLaunchKernelGGL(big_kernel, dim3(BIG_BLOCKS), dim3(256), 0, stream,
                     u, v, delta_t, edge_f, w_hist, returns, cov, combined,
                     user_emb, item_emb, mem, w_ih, w_hh, b_ih, b_hh,
                     in_w, in_b, out_w, out_b, h_out, z_out);
  hipLaunchKernelGGL(top5_stage1, dim3(S1_BLOCKS), dim3(256), 0, stream,
                     combined, keys);
  hipLaunchKernelGGL(top5_stage2, dim3(16), dim3(256), 0, stream,
                     keys, v, pos_out, neg_out);
}

// Round 15
// 124.223 us; speedup vs baseline: 1.0908x; 1.0908x over previous
//
#include <hip/hip_runtime.h>
#include <math.h>

#define BB_ 4096      // batch
#define DD_ 64        // emb dim
#define NI_ 10000     // items

// R9 structure (best measured: 116.5us), single change: PLAIN loads (no NT) so
// cov can allocate in L2/L3 -> cross-replay Infinity-Cache reuse (~256MB of cov).
#define GRU_BLOCKS  256                   // 16 rows/block
#define ATT_BLOCKS  512                   // 8 rows/block
#define MV_BLOCKS   2500                  // 4 rows/block (wave-per-row)
#define BIG_BLOCKS  (GRU_BLOCKS + ATT_BLOCKS + MV_BLOCKS)

// shared LDS pool: 13312 floats = 53248 B -> 3 blocks/CU
#define LDSF 13312

#define S1_BLOCKS 40  // top-5 stage-1 blocks (250 items each)

typedef unsigned long long u64;
typedef float v4f __attribute__((ext_vector_type(4)));

// ---------------- threefry2x32 (JAX PRNG, key=42, partitionable path) ----------------
__device__ inline unsigned rotl32(unsigned x, unsigned r){ return (x<<r)|(x>>(32u-r)); }

__device__ inline float jax_uniform_key42(int i){
  const unsigned k0 = 0u, k1 = 42u;
  const unsigned ks2 = 0x1BD11BDAu ^ k0 ^ k1;
  unsigned x0 = 0u, x1 = (unsigned)i;               // counter (hi, lo) = (0, i)
  unsigned ks[3] = {k0, k1, ks2};
  x0 += ks[0]; x1 += ks[1];
  const unsigned R0[4] = {13u,15u,26u,6u};
  const unsigned R1[4] = {17u,29u,16u,24u};
  #pragma unroll
  for (int it = 0; it < 5; ++it){
    const unsigned* R = (it & 1) ? R1 : R0;
    #pragma unroll
    for (int j = 0; j < 4; ++j){ x0 += x1; x1 = rotl32(x1, R[j]); x1 ^= x0; }
    x0 += ks[(it+1)%3];
    x1 += ks[(it+2)%3] + (unsigned)(it+1);
  }
  unsigned bits = x0 ^ x1;                          // partitionable 32-bit tail
  unsigned f = (bits >> 9) | 0x3F800000u;
  return __uint_as_float(f) - 1.0f;
}

// ---------------- kernel 0: histogram of v (float counts) ----------------
__global__ __launch_bounds__(1024) void hist_kernel(
    const int* __restrict__ v, float* __restrict__ w_out)
{
  __shared__ float wl[NI_];
  const int tid = threadIdx.x;
  for (int i = tid; i < NI_; i += 1024) wl[i] = 0.0f;
  __syncthreads();
  for (int i = tid; i < BB_; i += 1024) atomicAdd(&wl[v[i]], 1.0f);
  __syncthreads();
  for (int i = tid; i < NI_; i += 1024) w_out[i] = wl[i];
}

__device__ inline float dot4v(v4f a, v4f b){
  return a.x*b.x + a.y*b.y + a.z*b.z + a.w*b.w;
}

// ---------------- BIG fused kernel: GRU | attn | matvec ----------------
__global__ __launch_bounds__(256, 3) void big_kernel(
    const int* __restrict__ u, const int* __restrict__ v,
    const float* __restrict__ delta_t, const float* __restrict__ edge_feat,
    const float* __restrict__ w_in, const float* __restrict__ returns,
    const float* __restrict__ cov, float* __restrict__ combined,
    const float* __restrict__ user_emb, const float* __restrict__ item_emb,
    const float* __restrict__ mem,
    const float* __restrict__ w_ih, const float* __restrict__ w_hh,
    const float* __restrict__ b_ih, const float* __restrict__ b_hh,
    const float* __restrict__ in_w, const float* __restrict__ in_b,
    const float* __restrict__ out_w, const float* __restrict__ out_b,
    float* __restrict__ h_new_out, float* __restrict__ z_out)
{
  __shared__ __align__(16) float S[LDSF];
  const int tid  = threadIdx.x;
  const int lane = tid & 63, wid = tid >> 6;
  const int bid  = blockIdx.x;

  if (bid >= GRU_BLOCKS + ATT_BLOCKS) {
    // ======== matvec: wave-per-row, 4 independent PLAIN load streams ========
    {
      const float4* src = (const float4*)w_in;
      float4* dst = (float4*)S;
      for (int i = tid; i < NI_/4; i += 256) dst[i] = src[i];
    }
    __syncthreads();

    const int row = (bid - (GRU_BLOCKS + ATT_BLOCKS)) * 4 + wid;
    const v4f* w4 = (const v4f*)S;
    const v4f* r4 = (const v4f*)(cov + (size_t)row * NI_);

    float a0 = 0.0f, a1 = 0.0f, a2 = 0.0f, a3 = 0.0f;
    int k = lane;
    // 9 full 4-stream iterations cover k in [0, 2304)
    #pragma unroll 1
    for (int it = 0; it < 9; ++it, k += 256) {
      v4f c0 = r4[k];
      v4f c1 = r4[k+64];
      v4f c2 = r4[k+128];
      v4f c3 = r4[k+192];
      v4f w0 = w4[k], w1 = w4[k+64], w2 = w4[k+128], w3 = w4[k+192];
      a0 += dot4v(c0, w0);
      a1 += dot4v(c1, w1);
      a2 += dot4v(c2, w2);
      a3 += dot4v(c3, w3);
    }
    // tail: k = 2304+lane, three 64-wide chunks -> [2304, 2496)
    #pragma unroll 1
    for (int it = 0; it < 3; ++it, k += 64) {
      v4f c0 = r4[k];
      a0 += dot4v(c0, w4[k]);
    }
    // final 4 elements [2496, 2500)
    if (lane < 4) {
      v4f c0 = r4[2496 + lane];
      a1 += dot4v(c0, w4[2496 + lane]);
    }
    float acc = (a0 + a1) + (a2 + a3);
    #pragma unroll
    for (int off = 32; off > 0; off >>= 1) acc += __shfl_xor(acc, off);

    if (lane == 0) {
      float cov_val = acc * (1.0f / (float)BB_);
      float mv = returns[row] - 0.5f * cov_val;       // GAMMA = 1
      float pref = jax_uniform_key42(row);
      combined[row] = 0.5f * mv + 0.5f * pref;        // LAM = 0.5
    }
  } else if (bid < GRU_BLOCKS) {
    // ======== GRU (chunk-staged: 3 chunks of <=66x193 floats) ========
    float* T  = S;
    float* BI = S + 12738;
    float* BH = S + 12930;
    const int rowbase = bid * 16 + wid * 4;

    if (tid < 192) { BI[tid] = b_ih[tid]; BH[tid] = b_hh[tid]; }

    float u_d[4], v_d[4], h_d[4], dt[4], ef[4];
    int bb[4];
    #pragma unroll
    for (int rr = 0; rr < 4; ++rr) {
      int b = rowbase + rr; bb[rr] = b;
      int uu = u[b], vv = v[b];
      u_d[rr] = user_emb[uu*64 + lane];
      v_d[rr] = item_emb[vv*64 + lane];
      h_d[rr] = mem[uu*64 + lane];
      dt[rr]  = delta_t[b];
      ef[rr]  = edge_feat[b];
    }

    // ---- chunk 0: W_ih cols 0..63 (u_emb) ----
    for (int idx = tid; idx < 64*192; idx += 256) {
      int o = idx >> 6, j = idx & 63;
      T[j*193 + o] = w_ih[o*130 + j];
    }
    __syncthreads();

    float biR = BI[lane], biZ = BI[64+lane], biN = BI[128+lane];
    float bhR = BH[lane], bhZ = BH[64+lane], bhN = BH[128+lane];
    float accR[4], accZ[4], accN[4], hN[4];
    #pragma unroll
    for (int rr = 0; rr < 4; ++rr) { accR[rr]=biR+bhR; accZ[rr]=biZ+bhZ; accN[rr]=biN; hN[rr]=bhN; }

    for (int j = 0; j < 64; ++j) {
      float wR = T[j*193 + lane], wZ = T[j*193 + 64 + lane], wN = T[j*193 + 128 + lane];
      #pragma unroll
      for (int rr = 0; rr < 4; ++rr) {
        float m = __shfl(u_d[rr], j);
        accR[rr] = fmaf(wR, m, accR[rr]); accZ[rr] = fmaf(wZ, m, accZ[rr]); accN[rr] = fmaf(wN, m, accN[rr]);
      }
    }
    __syncthreads();

    // ---- chunk 1: W_ih cols 64..127 (v_emb) ----
    for (int idx = tid; idx < 64*192; idx += 256) {
      int o = idx >> 6, j = idx & 63;
      T[j*193 + o] = w_ih[o*130 + 64 + j];
    }
    __syncthreads();
    for (int j = 0; j < 64; ++j) {
      float wR = T[j*193 + lane], wZ = T[j*193 + 64 + lane], wN = T[j*193 + 128 + lane];
      #pragma unroll
      for (int rr = 0; rr < 4; ++rr) {
        float m = __shfl(v_d[rr], j);
        accR[rr] = fmaf(wR, m, accR[rr]); accZ[rr] = fmaf(wZ, m, accZ[rr]); accN[rr] = fmaf(wN, m, accN[rr]);
      }
    }
    __syncthreads();

    // ---- chunk 2: W_ih cols 128,129 (dt, ef) + W_hh (h) ----
    for (int idx = tid; idx < 384; idx += 256) {
      int o = idx >> 1, c = idx & 1;
      T[c*193 + o] = w_ih[o*130 + 128 + c];
    }
    for (int idx = tid; idx < 64*192; idx += 256) {
      int o = idx >> 6, jj = idx & 63;
      T[(2+jj)*193 + o] = w_hh[idx];
    }
    __syncthreads();
    {
      float wR = T[lane], wZ = T[64 + lane], wN = T[128 + lane];
      float eR = T[193 + lane], eZ = T[193 + 64 + lane], eN = T[193 + 128 + lane];
      #pragma unroll
      for (int rr = 0; rr < 4; ++rr) {
        accR[rr] = fmaf(wR, dt[rr], accR[rr]); accZ[rr] = fmaf(wZ, dt[rr], accZ[rr]); accN[rr] = fmaf(wN, dt[rr], accN[rr]);
        accR[rr] = fmaf(eR, ef[rr], accR[rr]); accZ[rr] = fmaf(eZ, ef[rr], accZ[rr]); accN[rr] = fmaf(eN, ef[rr], accN[rr]);
      }
    }
    for (int jj = 0; jj < 64; ++jj) {
      int base = (2+jj)*193;
      float wR = T[base + lane], wZ = T[base + 64 + lane], wN = T[base + 128 + lane];
      #pragma unroll
      for (int rr = 0; rr < 4; ++rr) {
        float m = __shfl(h_d[rr], jj);
        accR[rr] = fmaf(wR, m, accR[rr]); accZ[rr] = fmaf(wZ, m, accZ[rr]); hN[rr] = fmaf(wN, m, hN[rr]);
      }
    }

    #pragma unroll
    for (int rr = 0; rr < 4; ++rr) {
      float r = 1.0f / (1.0f + expf(-accR[rr]));
      float z = 1.0f / (1.0f + expf(-accZ[rr]));
      float n = tanhf(accN[rr] + r * hN[rr]);
      float hn = (1.0f - z) * n + z * h_d[rr];
      h_new_out[bb[rr]*64 + lane] = hn;
    }
  } else {
    // ======== attn (per-gate chunk staging) ========
    float* C    = S;
    float* OT   = S + 4160;
    float* BIN  = S + 8320;
    float* BOUT = S + 8512;
    const int abid = bid - GRU_BLOCKS;
    const int rowbase = abid * 8 + wid * 2;

    for (int idx = tid; idx < 64*64; idx += 256) {
      int k = idx >> 6, j = idx & 63;
      OT[j*65 + k] = out_w[idx];
    }
    if (tid < 192) BIN[tid] = in_b[tid];
    if (tid < 64)  BOUT[tid] = out_b[tid];

    float u_d[2], x1_d[2];
    int bb[2];
    #pragma unroll
    for (int rr = 0; rr < 2; ++rr) {
      int b = rowbase + rr; bb[rr] = b;
      int uu = u[b], vv = v[b];
      float ef = edge_feat[b];
      u_d[rr]  = user_emb[uu*64 + lane];
      x1_d[rr] = item_emb[vv*64 + lane] + ef;
    }

    float q0[2], k0[2], k1[2], v0[2], v1[2];

    // gate 0: q (token 0 only)
    for (int idx = tid; idx < 4096; idx += 256) {
      int o = idx >> 6, j = idx & 63;
      C[j*65 + o] = in_w[o*64 + j];
    }
    __syncthreads();
    {
      float bq = BIN[lane];
      #pragma unroll
      for (int rr = 0; rr < 2; ++rr) q0[rr] = bq;
      for (int j = 0; j < 64; ++j) {
        float wq = C[j*65 + lane];
        #pragma unroll
        for (int rr = 0; rr < 2; ++rr) q0[rr] = fmaf(wq, __shfl(u_d[rr], j), q0[rr]);
      }
    }
    __syncthreads();

    // gate 1: k (both tokens)
    for (int idx = tid; idx < 4096; idx += 256) {
      int o = idx >> 6, j = idx & 63;
      C[j*65 + o] = in_w[(64+o)*64 + j];
    }
    __syncthreads();
    {
      float bk = BIN[64+lane];
      #pragma unroll
      for (int rr = 0; rr < 2; ++rr) { k0[rr] = bk; k1[rr] = bk; }
      for (int j = 0; j < 64; ++j) {
        float wk = C[j*65 + lane];
        #pragma unroll
        for (int rr = 0; rr < 2; ++rr) {
          k0[rr] = fmaf(wk, __shfl(u_d[rr], j),  k0[rr]);
          k1[rr] = fmaf(wk, __shfl(x1_d[rr], j), k1[rr]);
        }
      }
    }
    __syncthreads();

    // gate 2: v (both tokens)
    for (int idx = tid; idx < 4096; idx += 256) {
      int o = idx >> 6, j = idx & 63;
      C[j*65 + o] = in_w[(128+o)*64 + j];
    }
    __syncthreads();
    {
      float bv = BIN[128+lane];
      #pragma unroll
      for (int rr = 0; rr < 2; ++rr) { v0[rr] = bv; v1[rr] = bv; }
      for (int j = 0; j < 64; ++j) {
        float wv = C[j*65 + lane];
        #pragma unroll
        for (int rr = 0; rr < 2; ++rr) {
          v0[rr] = fmaf(wv, __shfl(u_d[rr], j),  v0[rr]);
          v1[rr] = fmaf(wv, __shfl(x1_d[rr], j), v1[rr]);
        }
      }
    }

    #pragma unroll
    for (int rr = 0; rr < 2; ++rr) {
      float p0 = q0[rr]*k0[rr], p1 = q0[rr]*k1[rr];
      #pragma unroll
      for (int off = 1; off < 16; off <<= 1) { p0 += __shfl_xor(p0, off); p1 += __shfl_xor(p1, off); }
      float s0 = p0 * 0.25f, s1 = p1 * 0.25f;
      float m  = fmaxf(s0, s1);
      float e0 = expf(s0 - m), e1 = expf(s1 - m);
      float inv = 1.0f / (e0 + e1);
      float o_d = (e0 * v0[rr] + e1 * v1[rr]) * inv;
      float zacc = BOUT[lane];
      for (int j = 0; j < 64; ++j)
        zacc = fmaf(OT[j*65 + lane], __shfl(o_d, j), zacc);
      z_out[bb[rr]*64 + lane] = zacc;
    }
  }
}

// ---------------- top-5 helpers ----------------
__device__ inline u64 shfl_down_u64(u64 x, int off){
  unsigned lo = (unsigned)(x & 0xFFFFFFFFull), hi = (unsigned)(x >> 32);
  lo = __shfl_down(lo, off); hi = __shfl_down(hi, off);
  return ((u64)hi << 32) | (u64)lo;
}

__device__ inline u64 make_key(float val, int i){
  unsigned u = __float_as_uint(val);
  u ^= (u >> 31) ? 0xFFFFFFFFu : 0x80000000u;       // order-preserving float->uint
  return ((u64)u << 32) | (u64)(0xFFFFFFFFu - (unsigned)i); // tie: lower idx wins
}

// ---------------- kernel 2a: per-slice top-5 (40 blocks, 250 items each) ----------------
__global__ __launch_bounds__(256) void top5_stage1(
    const float* __restrict__ combined, u64* __restrict__ keys_out)
{
  __shared__ u64 redL[4];
  __shared__ u64 sel;
  const int tid = threadIdx.x, lane = tid & 63, wid = tid >> 6;
  const int i = blockIdx.x * 250 + tid;

  u64 key = 0ull;
  if (tid < 250 && i < NI_) key = make_key(combined[i], i);

  for (int r = 0; r < 5; ++r) {
    u64 best = key;
    #pragma unroll
    for (int off = 32; off > 0; off >>= 1) {
      u64 o = shfl_down_u64(best, off);
      if (o > best) best = o;
    }
    if (lane == 0) redL[wid] = best;
    __syncthreads();
    if (tid == 0) {
      u64 b = redL[0];
      for (int wv = 1; wv < 4; ++wv) if (redL[wv] > b) b = redL[wv];
      sel = b;
      keys_out[blockIdx.x * 5 + r] = b;
    }
    __syncthreads();
    if (key == sel) key = 0ull;
  }
}

// ---------------- kernel 2b: 16 blocks; each reduces 200 keys + emits 256 rows ----------------
__global__ __launch_bounds__(256) void top5_stage2(
    const u64* __restrict__ keys_in, const int* __restrict__ v,
    float* __restrict__ pos_out, float* __restrict__ neg_out)
{
  __shared__ u64 redL[4];
  __shared__ u64 sel;
  __shared__ int chosen[5];
  const int tid = threadIdx.x, lane = tid & 63, wid = tid >> 6;

  u64 key = (tid < 5 * S1_BLOCKS) ? keys_in[tid] : 0ull;

  for (int r = 0; r < 5; ++r) {
    u64 best = key;
    #pragma unroll
    for (int off = 32; off > 0; off >>= 1) {
      u64 o = shfl_down_u64(best, off);
      if (o > best) best = o;
    }
    if (lane == 0) redL[wid] = best;
    __syncthreads();
    if (tid == 0) {
      u64 b = redL[0];
      for (int wv = 1; wv < 4; ++wv) if (redL[wv] > b) b = redL[wv];
      sel = b;
      chosen[r] = (int)(0xFFFFFFFFu - (unsigned)(b & 0xFFFFFFFFull));
    }
    __syncthreads();
    if (key == sel) key = 0ull;
  }

  const int b = blockIdx.x * 256 + tid;   // 16 blocks x 256 = 4096 rows
  int vb = v[b];
  int f[4]; int n = 0;
  #pragma unroll
  for (int c = 0; c < 5; ++c) { if (n < 4 && chosen[c] != vb) f[n++] = chosen[c]; }
  pos_out[b]       = (float)f[0];
  neg_out[b*3 + 0] = (float)f[1];
  neg_out[b*3 + 1] = (float)f[2];
  neg_out[b*3 + 2] = (float)f[3];
}

// ---------------- launch ----------------
extern "C" void kernel_launch(void* const* d_in, const int* in_sizes, int n_in,
                              void* d_out, int out_size, void* d_ws, size_t ws_size,
                              hipStream_t stream)
{
  const int*   u        = (const int*)d_in[0];
  const int*   v        = (const int*)d_in[1];
  /* t = d_in[2] unused */
  const float* delta_t  = (const float*)d_in[3];
  const float* edge_f   = (const float*)d_in[4];
  const float* returns  = (const float*)d_in[5];
  const float* cov      = (const float*)d_in[6];
  const float* user_emb = (const float*)d_in[7];
  const float* item_emb = (const float*)d_in[8];
  const float* mem      = (const float*)d_in[9];
  const float* w_ih     = (const float*)d_in[10];
  const float* w_hh     = (const float*)d_in[11];
  const float* b_ih     = (const float*)d_in[12];
  const float* b_hh     = (const float*)d_in[13];
  const float* in_w     = (const float*)d_in[14];
  const float* in_b     = (const float*)d_in[15];
  const float* out_w    = (const float*)d_in[16];
  const float* out_b    = (const float*)d_in[17];

  float* out     = (float*)d_out;
  float* z_out   = out;                    // B*D
  float* h_out   = out + BB_*DD_;          // B*D
  float* pos_out = out + 2*BB_*DD_;        // B
  float* neg_out = out + 2*BB_*DD_ + BB_;  // B*3

  float* ws        = (float*)d_ws;
  float* w_hist    = ws;                   // NI_ floats (16B-aligned)
  float* combined  = ws + 10240;           // NI_ floats
  u64*   keys      = (u64*)(ws + 20480);   // S1_BLOCKS*5 u64

  hipLaunchKernelGGL(hist_kernel, dim3(1), dim3(1024), 0, stream, v, w_hist);
  hipLaunchKernelGGL(big_kernel, dim3(BIG_BLOCKS), dim3(256), 0, stream,
                     u, v, delta_t, edge_f, w_hist, returns, cov, combined,
                     user_emb, item_emb, mem, w_ih, w_hh, b_ih, b_hh,
                     in_w, in_b, out_w, out_b, h_out, z_out);
  hipLaunchKernelGGL(top5_stage1, dim3(S1_BLOCKS), dim3(256), 0, stream,
                     combined, keys);
  hipLaunchKernelGGL(top5_stage2, dim3(16), dim3(256), 0, stream,
                     keys, v, pos_out, neg_out);
}

// Round 16
// 115.620 us; speedup vs baseline: 1.1720x; 1.0744x over previous
//
#include <hip/hip_runtime.h>
#include <math.h>

#define BB_ 4096      // batch
#define DD_ 64        // emb dim
#define NI_ 10000     // items

// R9 structure restored (best measured: 116.5us): NT loads, 4 streams,
// unroll-1, 3 blk/CU, compute-first contiguous. Only change vs R9: hist is
// hipMemsetAsync + 16-block global-atomic kernel (was 1-block serial, ~8us).
#define GRU_BLOCKS  256                   // 16 rows/block
#define ATT_BLOCKS  512                   // 8 rows/block
#define MV_BLOCKS   2500                  // 4 rows/block (wave-per-row)
#define BIG_BLOCKS  (GRU_BLOCKS + ATT_BLOCKS + MV_BLOCKS)

// shared LDS pool: 13312 floats = 53248 B -> 3 blocks/CU
#define LDSF 13312

#define S1_BLOCKS 40  // top-5 stage-1 blocks (250 items each)

typedef unsigned long long u64;
typedef float v4f __attribute__((ext_vector_type(4)));

// ---------------- threefry2x32 (JAX PRNG, key=42, partitionable path) ----------------
__device__ inline unsigned rotl32(unsigned x, unsigned r){ return (x<<r)|(x>>(32u-r)); }

__device__ inline float jax_uniform_key42(int i){
  const unsigned k0 = 0u, k1 = 42u;
  const unsigned ks2 = 0x1BD11BDAu ^ k0 ^ k1;
  unsigned x0 = 0u, x1 = (unsigned)i;               // counter (hi, lo) = (0, i)
  unsigned ks[3] = {k0, k1, ks2};
  x0 += ks[0]; x1 += ks[1];
  const unsigned R0[4] = {13u,15u,26u,6u};
  const unsigned R1[4] = {17u,29u,16u,24u};
  #pragma unroll
  for (int it = 0; it < 5; ++it){
    const unsigned* R = (it & 1) ? R1 : R0;
    #pragma unroll
    for (int j = 0; j < 4; ++j){ x0 += x1; x1 = rotl32(x1, R[j]); x1 ^= x0; }
    x0 += ks[(it+1)%3];
    x1 += ks[(it+2)%3] + (unsigned)(it+1);
  }
  unsigned bits = x0 ^ x1;                          // partitionable 32-bit tail
  unsigned f = (bits >> 9) | 0x3F800000u;
  return __uint_as_float(f) - 1.0f;
}

// ---------------- kernel 0: parallel histogram (w_hist pre-zeroed by memset) ----------------
__global__ __launch_bounds__(256) void hist_kernel(
    const int* __restrict__ v, float* __restrict__ w_out)
{
  const int i = blockIdx.x * 256 + threadIdx.x;     // 16 blocks x 256 = 4096
  atomicAdd(&w_out[v[i]], 1.0f);
}

__device__ inline float dot4v(v4f a, v4f b){
  return a.x*b.x + a.y*b.y + a.z*b.z + a.w*b.w;
}

// ---------------- BIG fused kernel: GRU | attn | matvec ----------------
__global__ __launch_bounds__(256, 3) void big_kernel(
    const int* __restrict__ u, const int* __restrict__ v,
    const float* __restrict__ delta_t, const float* __restrict__ edge_feat,
    const float* __restrict__ w_in, const float* __restrict__ returns,
    const float* __restrict__ cov, float* __restrict__ combined,
    const float* __restrict__ user_emb, const float* __restrict__ item_emb,
    const float* __restrict__ mem,
    const float* __restrict__ w_ih, const float* __restrict__ w_hh,
    const float* __restrict__ b_ih, const float* __restrict__ b_hh,
    const float* __restrict__ in_w, const float* __restrict__ in_b,
    const float* __restrict__ out_w, const float* __restrict__ out_b,
    float* __restrict__ h_new_out, float* __restrict__ z_out)
{
  __shared__ __align__(16) float S[LDSF];
  const int tid  = threadIdx.x;
  const int lane = tid & 63, wid = tid >> 6;
  const int bid  = blockIdx.x;

  if (bid >= GRU_BLOCKS + ATT_BLOCKS) {
    // ======== matvec: wave-per-row, 4 NT load streams, w staged in LDS ========
    {
      const float4* src = (const float4*)w_in;
      float4* dst = (float4*)S;
      for (int i = tid; i < NI_/4; i += 256) dst[i] = src[i];
    }
    __syncthreads();

    const int row = (bid - (GRU_BLOCKS + ATT_BLOCKS)) * 4 + wid;
    const v4f* w4 = (const v4f*)S;
    const v4f* r4 = (const v4f*)(cov + (size_t)row * NI_);

    float a0 = 0.0f, a1 = 0.0f, a2 = 0.0f, a3 = 0.0f;
    int k = lane;
    // 9 full 4-stream iterations cover k in [0, 2304)
    #pragma unroll 1
    for (int it = 0; it < 9; ++it, k += 256) {
      v4f c0 = __builtin_nontemporal_load(&r4[k]);
      v4f c1 = __builtin_nontemporal_load(&r4[k+64]);
      v4f c2 = __builtin_nontemporal_load(&r4[k+128]);
      v4f c3 = __builtin_nontemporal_load(&r4[k+192]);
      v4f w0 = w4[k], w1 = w4[k+64], w2 = w4[k+128], w3 = w4[k+192];
      a0 += dot4v(c0, w0);
      a1 += dot4v(c1, w1);
      a2 += dot4v(c2, w2);
      a3 += dot4v(c3, w3);
    }
    // tail: k = 2304+lane, three 64-wide chunks -> [2304, 2496)
    #pragma unroll 1
    for (int it = 0; it < 3; ++it, k += 64) {
      v4f c0 = __builtin_nontemporal_load(&r4[k]);
      a0 += dot4v(c0, w4[k]);
    }
    // final 4 elements [2496, 2500)
    if (lane < 4) {
      v4f c0 = __builtin_nontemporal_load(&r4[2496 + lane]);
      a1 += dot4v(c0, w4[2496 + lane]);
    }
    float acc = (a0 + a1) + (a2 + a3);
    #pragma unroll
    for (int off = 32; off > 0; off >>= 1) acc += __shfl_xor(acc, off);

    if (lane == 0) {
      float cov_val = acc * (1.0f / (float)BB_);
      float mv = returns[row] - 0.5f * cov_val;       // GAMMA = 1
      float pref = jax_uniform_key42(row);
      combined[row] = 0.5f * mv + 0.5f * pref;        // LAM = 0.5
    }
  } else if (bid < GRU_BLOCKS) {
    // ======== GRU (chunk-staged: 3 chunks of <=66x193 floats) ========
    float* T  = S;
    float* BI = S + 12738;
    float* BH = S + 12930;
    const int rowbase = bid * 16 + wid * 4;

    if (tid < 192) { BI[tid] = b_ih[tid]; BH[tid] = b_hh[tid]; }

    float u_d[4], v_d[4], h_d[4], dt[4], ef[4];
    int bb[4];
    #pragma unroll
    for (int rr = 0; rr < 4; ++rr) {
      int b = rowbase + rr; bb[rr] = b;
      int uu = u[b], vv = v[b];
      u_d[rr] = user_emb[uu*64 + lane];
      v_d[rr] = item_emb[vv*64 + lane];
      h_d[rr] = mem[uu*64 + lane];
      dt[rr]  = delta_t[b];
      ef[rr]  = edge_feat[b];
    }

    // ---- chunk 0: W_ih cols 0..63 (u_emb) ----
    for (int idx = tid; idx < 64*192; idx += 256) {
      int o = idx >> 6, j = idx & 63;
      T[j*193 + o] = w_ih[o*130 + j];
    }
    __syncthreads();

    float biR = BI[lane], biZ = BI[64+lane], biN = BI[128+lane];
    float bhR = BH[lane], bhZ = BH[64+lane], bhN = BH[128+lane];
    float accR[4], accZ[4], accN[4], hN[4];
    #pragma unroll
    for (int rr = 0; rr < 4; ++rr) { accR[rr]=biR+bhR; accZ[rr]=biZ+bhZ; accN[rr]=biN; hN[rr]=bhN; }

    for (int j = 0; j < 64; ++j) {
      float wR = T[j*193 + lane], wZ = T[j*193 + 64 + lane], wN = T[j*193 + 128 + lane];
      #pragma unroll
      for (int rr = 0; rr < 4; ++rr) {
        float m = __shfl(u_d[rr], j);
        accR[rr] = fmaf(wR, m, accR[rr]); accZ[rr] = fmaf(wZ, m, accZ[rr]); accN[rr] = fmaf(wN, m, accN[rr]);
      }
    }
    __syncthreads();

    // ---- chunk 1: W_ih cols 64..127 (v_emb) ----
    for (int idx = tid; idx < 64*192; idx += 256) {
      int o = idx >> 6, j = idx & 63;
      T[j*193 + o] = w_ih[o*130 + 64 + j];
    }
    __syncthreads();
    for (int j = 0; j < 64; ++j) {
      float wR = T[j*193 + lane], wZ = T[j*193 + 64 + lane], wN = T[j*193 + 128 + lane];
      #pragma unroll
      for (int rr = 0; rr < 4; ++rr) {
        float m = __shfl(v_d[rr], j);
        accR[rr] = fmaf(wR, m, accR[rr]); accZ[rr] = fmaf(wZ, m, accZ[rr]); accN[rr] = fmaf(wN, m, accN[rr]);
      }
    }
    __syncthreads();

    // ---- chunk 2: W_ih cols 128,129 (dt, ef) + W_hh (h) ----
    for (int idx = tid; idx < 384; idx += 256) {
      int o = idx >> 1, c = idx & 1;
      T[c*193 + o] = w_ih[o*130 + 128 + c];
    }
    for (int idx = tid; idx < 64*192; idx += 256) {
      int o = idx >> 6, jj = idx & 63;
      T[(2+jj)*193 + o] = w_hh[idx];
    }
    __syncthreads();
    {
      float wR = T[lane], wZ = T[64 + lane], wN = T[128 + lane];
      float eR = T[193 + lane], eZ = T[193 + 64 + lane], eN = T[193 + 128 + lane];
      #pragma unroll
      for (int rr = 0; rr < 4; ++rr) {
        accR[rr] = fmaf(wR, dt[rr], accR[rr]); accZ[rr] = fmaf(wZ, dt[rr], accZ[rr]); accN[rr] = fmaf(wN, dt[rr], accN[rr]);
        accR[rr] = fmaf(eR, ef[rr], accR[rr]); accZ[rr] = fmaf(eZ, ef[rr], accZ[rr]); accN[rr] = fmaf(eN, ef[rr], accN[rr]);
      }
    }
    for (int jj = 0; jj < 64; ++jj) {
      int base = (2+jj)*193;
      float wR = T[base + lane], wZ = T[base + 64 + lane], wN = T[base + 128 + lane];
      #pragma unroll
      for (int rr = 0; rr < 4; ++rr) {
        float m = __shfl(h_d[rr], jj);
        accR[rr] = fmaf(wR, m, accR[rr]); accZ[rr] = fmaf(wZ, m, accZ[rr]); hN[rr] = fmaf(wN, m, hN[rr]);
      }
    }

    #pragma unroll
    for (int rr = 0; rr < 4; ++rr) {
      float r = 1.0f / (1.0f + expf(-accR[rr]));
      float z = 1.0f / (1.0f + expf(-accZ[rr]));
      float n = tanhf(accN[rr] + r * hN[rr]);
      float hn = (1.0f - z) * n + z * h_d[rr];
      h_new_out[bb[rr]*64 + lane] = hn;
    }
  } else {
    // ======== attn (per-gate chunk staging) ========
    float* C    = S;
    float* OT   = S + 4160;
    float* BIN  = S + 8320;
    float* BOUT = S + 8512;
    const int abid = bid - GRU_BLOCKS;
    const int rowbase = abid * 8 + wid * 2;

    for (int idx = tid; idx < 64*64; idx += 256) {
      int k = idx >> 6, j = idx & 63;
      OT[j*65 + k] = out_w[idx];
    }
    if (tid < 192) BIN[tid] = in_b[tid];
    if (tid < 64)  BOUT[tid] = out_b[tid];

    float u_d[2], x1_d[2];
    int bb[2];
    #pragma unroll
    for (int rr = 0; rr < 2; ++rr) {
      int b = rowbase + rr; bb[rr] = b;
      int uu = u[b], vv = v[b];
      float ef = edge_feat[b];
      u_d[rr]  = user_emb[uu*64 + lane];
      x1_d[rr] = item_emb[vv*64 + lane] + ef;
    }

    float q0[2], k0[2], k1[2], v0[2], v1[2];

    // gate 0: q (token 0 only)
    for (int idx = tid; idx < 4096; idx += 256) {
      int o = idx >> 6, j = idx & 63;
      C[j*65 + o] = in_w[o*64 + j];
    }
    __syncthreads();
    {
      float bq = BIN[lane];
      #pragma unroll
      for (int rr = 0; rr < 2; ++rr) q0[rr] = bq;
      for (int j = 0; j < 64; ++j) {
        float wq = C[j*65 + lane];
        #pragma unroll
        for (int rr = 0; rr < 2; ++rr) q0[rr] = fmaf(wq, __shfl(u_d[rr], j), q0[rr]);
      }
    }
    __syncthreads();

    // gate 1: k (both tokens)
    for (int idx = tid; idx < 4096; idx += 256) {
      int o = idx >> 6, j = idx & 63;
      C[j*65 + o] = in_w[(64+o)*64 + j];
    }
    __syncthreads();
    {
      float bk = BIN[64+lane];
      #pragma unroll
      for (int rr = 0; rr < 2; ++rr) { k0[rr] = bk; k1[rr] = bk; }
      for (int j = 0; j < 64; ++j) {
        float wk = C[j*65 + lane];
        #pragma unroll
        for (int rr = 0; rr < 2; ++rr) {
          k0[rr] = fmaf(wk, __shfl(u_d[rr], j),  k0[rr]);
          k1[rr] = fmaf(wk, __shfl(x1_d[rr], j), k1[rr]);
        }
      }
    }
    __syncthreads();

    // gate 2: v (both tokens)
    for (int idx = tid; idx < 4096; idx += 256) {
      int o = idx >> 6, j = idx & 63;
      C[j*65 + o] = in_w[(128+o)*64 + j];
    }
    __syncthreads();
    {
      float bv = BIN[128+lane];
      #pragma unroll
      for (int rr = 0; rr < 2; ++rr) { v0[rr] = bv; v1[rr] = bv; }
      for (int j = 0; j < 64; ++j) {
        float wv = C[j*65 + lane];
        #pragma unroll
        for (int rr = 0; rr < 2; ++rr) {
          v0[rr] = fmaf(wv, __shfl(u_d[rr], j),  v0[rr]);
          v1[rr] = fmaf(wv, __shfl(x1_d[rr], j), v1[rr]);
        }
      }
    }

    #pragma unroll
    for (int rr = 0; rr < 2; ++rr) {
      float p0 = q0[rr]*k0[rr], p1 = q0[rr]*k1[rr];
      #pragma unroll
      for (int off = 1; off < 16; off <<= 1) { p0 += __shfl_xor(p0, off); p1 += __shfl_xor(p1, off); }
      float s0 = p0 * 0.25f, s1 = p1 * 0.25f;
      float m  = fmaxf(s0, s1);
      float e0 = expf(s0 - m), e1 = expf(s1 - m);
      float inv = 1.0f / (e0 + e1);
      float o_d = (e0 * v0[rr] + e1 * v1[rr]) * inv;
      float zacc = BOUT[lane];
      for (int j = 0; j < 64; ++j)
        zacc = fmaf(OT[j*65 + lane], __shfl(o_d, j), zacc);
      z_out[bb[rr]*64 + lane] = zacc;
    }
  }
}

// ---------------- top-5 helpers ----------------
__device__ inline u64 shfl_down_u64(u64 x, int off){
  unsigned lo = (unsigned)(x & 0xFFFFFFFFull), hi = (unsigned)(x >> 32);
  lo = __shfl_down(lo, off); hi = __shfl_down(hi, off);
  return ((u64)hi << 32) | (u64)lo;
}

__device__ inline u64 make_key(float val, int i){
  unsigned u = __float_as_uint(val);
  u ^= (u >> 31) ? 0xFFFFFFFFu : 0x80000000u;       // order-preserving float->uint
  return ((u64)u << 32) | (u64)(0xFFFFFFFFu - (unsigned)i); // tie: lower idx wins
}

// ---------------- kernel 2a: per-slice top-5 (40 blocks, 250 items each) ----------------
__global__ __launch_bounds__(256) void top5_stage1(
    const float* __restrict__ combined, u64* __restrict__ keys_out)
{
  __shared__ u64 redL[4];
  __shared__ u64 sel;
  const int tid = threadIdx.x, lane = tid & 63, wid = tid >> 6;
  const int i = blockIdx.x * 250 + tid;

  u64 key = 0ull;
  if (tid < 250 && i < NI_) key = make_key(combined[i], i);

  for (int r = 0; r < 5; ++r) {
    u64 best = key;
    #pragma unroll
    for (int off = 32; off > 0; off >>= 1) {
      u64 o = shfl_down_u64(best, off);
      if (o > best) best = o;
    }
    if (lane == 0) redL[wid] = best;
    __syncthreads();
    if (tid == 0) {
      u64 b = redL[0];
      for (int wv = 1; wv < 4; ++wv) if (redL[wv] > b) b = redL[wv];
      sel = b;
      keys_out[blockIdx.x * 5 + r] = b;
    }
    __syncthreads();
    if (key == sel) key = 0ull;
  }
}

// ---------------- kernel 2b: 16 blocks; each reduces 200 keys + emits 256 rows ----------------
__global__ __launch_bounds__(256) void top5_stage2(
    const u64* __restrict__ keys_in, const int* __restrict__ v,
    float* __restrict__ pos_out, float* __restrict__ neg_out)
{
  __shared__ u64 redL[4];
  __shared__ u64 sel;
  __shared__ int chosen[5];
  const int tid = threadIdx.x, lane = tid & 63, wid = tid >> 6;

  u64 key = (tid < 5 * S1_BLOCKS) ? keys_in[tid] : 0ull;

  for (int r = 0; r < 5; ++r) {
    u64 best = key;
    #pragma unroll
    for (int off = 32; off > 0; off >>= 1) {
      u64 o = shfl_down_u64(best, off);
      if (o > best) best = o;
    }
    if (lane == 0) redL[wid] = best;
    __syncthreads();
    if (tid == 0) {
      u64 b = redL[0];
      for (int wv = 1; wv < 4; ++wv) if (redL[wv] > b) b = redL[wv];
      sel = b;
      chosen[r] = (int)(0xFFFFFFFFu - (unsigned)(b & 0xFFFFFFFFull));
    }
    __syncthreads();
    if (key == sel) key = 0ull;
  }

  const int b = blockIdx.x * 256 + tid;   // 16 blocks x 256 = 4096 rows
  int vb = v[b];
  int f[4]; int n = 0;
  #pragma unroll
  for (int c = 0; c < 5; ++c) { if (n < 4 && chosen[c] != vb) f[n++] = chosen[c]; }
  pos_out[b]       = (float)f[0];
  neg_out[b*3 + 0] = (float)f[1];
  neg_out[b*3 + 1] = (float)f[2];
  neg_out[b*3 + 2] = (float)f[3];
}

// ---------------- launch ----------------
extern "C" void kernel_launch(void* const* d_in, const int* in_sizes, int n_in,
                              void* d_out, int out_size, void* d_ws, size_t ws_size,
                              hipStream_t stream)
{
  const int*   u        = (const int*)d_in[0];
  const int*   v        = (const int*)d_in[1];
  /* t = d_in[2] unused */
  const float* delta_t  = (const float*)d_in[3];
  const float* edge_f   = (const float*)d_in[4];
  const float* returns  = (const float*)d_in[5];
  const float* cov      = (const float*)d_in[6];
  const float* user_emb = (const float*)d_in[7];
  const float* item_emb = (const float*)d_in[8];
  const float* mem      = (const float*)d_in[9];
  const float* w_ih     = (const float*)d_in[10];
  const float* w_hh     = (const float*)d_in[11];
  const float* b_ih     = (const float*)d_in[12];
  const float* b_hh     = (const float*)d_in[13];
  const float* in_w     = (const float*)d_in[14];
  const float* in_b     = (const float*)d_in[15];
  const float* out_w    = (const float*)d_in[16];
  const float* out_b    = (const float*)d_in[17];

  float* out     = (float*)d_out;
  float* z_out   = out;                    // B*D
  float* h_out   = out + BB_*DD_;          // B*D
  float* pos_out = out + 2*BB_*DD_;        // B
  float* neg_out = out + 2*BB_*DD_ + BB_;  // B*3

  float* ws        = (float*)d_ws;
  float* w_hist    = ws;                   // NI_ floats (16B-aligned)
  float* combined  = ws + 10240;           // NI_ floats
  u64*   keys      = (u64*)(ws + 20480);   // S1_BLOCKS*5 u64

  hipMemsetAsync(w_hist, 0, NI_ * sizeof(float), stream);
  hipLaunchKernelGGL(hist_kernel, dim3(16), dim3(256), 0, stream, v, w_hist);
  hipLaunchKernelGGL(big_kernel, dim3(BIG_BLOCKS), dim3(256), 0, stream,
                     u, v, delta_t, edge_f, w_hist, returns, cov, combined,
                     user_emb, item_emb, mem, w_ih, w_hh, b_ih, b_hh,
                     in_w, in_b, out_w, out_b, h_out, z_out);
  hipLaunchKernelGGL(top5_stage1, dim3(S1_BLOCKS), dim3(256), 0, stream,
                     combined, keys);
  hipLaunchKernelGGL(top5_stage2, dim3(16), dim3(256), 0, stream,
                     keys, v, pos_out, neg_out);
}

// Round 17
// 112.934 us; speedup vs baseline: 1.1998x; 1.0238x over previous
//
#include <hip/hip_runtime.h>
#include <math.h>

#define BB_ 4096      // batch
#define DD_ 64        // emb dim
#define NI_ 10000     // items

// R16 structure (best measured: 115.6us). Single change: matvec inner loop
// widened 4 -> 6 independent NT streams (unroll-1; ~48 live VGPRs, safe at
// 3 blk/CU). Raises per-wave in-flight HBM bytes 4KB -> 6KB (72KB/CU).
#define GRU_BLOCKS  256                   // 16 rows/block
#define ATT_BLOCKS  512                   // 8 rows/block
#define MV_BLOCKS   2500                  // 4 rows/block (wave-per-row)
#define BIG_BLOCKS  (GRU_BLOCKS + ATT_BLOCKS + MV_BLOCKS)

// shared LDS pool: 13312 floats = 53248 B -> 3 blocks/CU
#define LDSF 13312

#define S1_BLOCKS 40  // top-5 stage-1 blocks (250 items each)

typedef unsigned long long u64;
typedef float v4f __attribute__((ext_vector_type(4)));

// ---------------- threefry2x32 (JAX PRNG, key=42, partitionable path) ----------------
__device__ inline unsigned rotl32(unsigned x, unsigned r){ return (x<<r)|(x>>(32u-r)); }

__device__ inline float jax_uniform_key42(int i){
  const unsigned k0 = 0u, k1 = 42u;
  const unsigned ks2 = 0x1BD11BDAu ^ k0 ^ k1;
  unsigned x0 = 0u, x1 = (unsigned)i;               // counter (hi, lo) = (0, i)
  unsigned ks[3] = {k0, k1, ks2};
  x0 += ks[0]; x1 += ks[1];
  const unsigned R0[4] = {13u,15u,26u,6u};
  const unsigned R1[4] = {17u,29u,16u,24u};
  #pragma unroll
  for (int it = 0; it < 5; ++it){
    const unsigned* R = (it & 1) ? R1 : R0;
    #pragma unroll
    for (int j = 0; j < 4; ++j){ x0 += x1; x1 = rotl32(x1, R[j]); x1 ^= x0; }
    x0 += ks[(it+1)%3];
    x1 += ks[(it+2)%3] + (unsigned)(it+1);
  }
  unsigned bits = x0 ^ x1;                          // partitionable 32-bit tail
  unsigned f = (bits >> 9) | 0x3F800000u;
  return __uint_as_float(f) - 1.0f;
}

// ---------------- kernel 0: parallel histogram (w_hist pre-zeroed by memset) ----------------
__global__ __launch_bounds__(256) void hist_kernel(
    const int* __restrict__ v, float* __restrict__ w_out)
{
  const int i = blockIdx.x * 256 + threadIdx.x;     // 16 blocks x 256 = 4096
  atomicAdd(&w_out[v[i]], 1.0f);
}

__device__ inline float dot4v(v4f a, v4f b){
  return a.x*b.x + a.y*b.y + a.z*b.z + a.w*b.w;
}

// ---------------- BIG fused kernel: GRU | attn | matvec ----------------
__global__ __launch_bounds__(256, 3) void big_kernel(
    const int* __restrict__ u, const int* __restrict__ v,
    const float* __restrict__ delta_t, const float* __restrict__ edge_feat,
    const float* __restrict__ w_in, const float* __restrict__ returns,
    const float* __restrict__ cov, float* __restrict__ combined,
    const float* __restrict__ user_emb, const float* __restrict__ item_emb,
    const float* __restrict__ mem,
    const float* __restrict__ w_ih, const float* __restrict__ w_hh,
    const float* __restrict__ b_ih, const float* __restrict__ b_hh,
    const float* __restrict__ in_w, const float* __restrict__ in_b,
    const float* __restrict__ out_w, const float* __restrict__ out_b,
    float* __restrict__ h_new_out, float* __restrict__ z_out)
{
  __shared__ __align__(16) float S[LDSF];
  const int tid  = threadIdx.x;
  const int lane = tid & 63, wid = tid >> 6;
  const int bid  = blockIdx.x;

  if (bid >= GRU_BLOCKS + ATT_BLOCKS) {
    // ======== matvec: wave-per-row, 6 NT load streams, w staged in LDS ========
    {
      const float4* src = (const float4*)w_in;
      float4* dst = (float4*)S;
      for (int i = tid; i < NI_/4; i += 256) dst[i] = src[i];
    }
    __syncthreads();

    const int row = (bid - (GRU_BLOCKS + ATT_BLOCKS)) * 4 + wid;
    const v4f* w4 = (const v4f*)S;
    const v4f* r4 = (const v4f*)(cov + (size_t)row * NI_);

    float a0 = 0.0f, a1 = 0.0f, a2 = 0.0f, a3 = 0.0f, a4 = 0.0f, a5 = 0.0f;
    int k = lane;
    // 6 full 6-stream iterations cover k in [0, 2304)
    #pragma unroll 1
    for (int it = 0; it < 6; ++it, k += 384) {
      v4f c0 = __builtin_nontemporal_load(&r4[k]);
      v4f c1 = __builtin_nontemporal_load(&r4[k+64]);
      v4f c2 = __builtin_nontemporal_load(&r4[k+128]);
      v4f c3 = __builtin_nontemporal_load(&r4[k+192]);
      v4f c4 = __builtin_nontemporal_load(&r4[k+256]);
      v4f c5 = __builtin_nontemporal_load(&r4[k+320]);
      v4f w0 = w4[k],     w1 = w4[k+64],  w2 = w4[k+128];
      v4f w3 = w4[k+192], w4v = w4[k+256], w5 = w4[k+320];
      a0 += dot4v(c0, w0);
      a1 += dot4v(c1, w1);
      a2 += dot4v(c2, w2);
      a3 += dot4v(c3, w3);
      a4 += dot4v(c4, w4v);
      a5 += dot4v(c5, w5);
    }
    // tail: k = 2304+lane, three 64-wide chunks -> [2304, 2496)
    #pragma unroll 1
    for (int it = 0; it < 3; ++it, k += 64) {
      v4f c0 = __builtin_nontemporal_load(&r4[k]);
      a0 += dot4v(c0, w4[k]);
    }
    // final 4 elements [2496, 2500)
    if (lane < 4) {
      v4f c0 = __builtin_nontemporal_load(&r4[2496 + lane]);
      a1 += dot4v(c0, w4[2496 + lane]);
    }
    float acc = ((a0 + a1) + (a2 + a3)) + (a4 + a5);
    #pragma unroll
    for (int off = 32; off > 0; off >>= 1) acc += __shfl_xor(acc, off);

    if (lane == 0) {
      float cov_val = acc * (1.0f / (float)BB_);
      float mv = returns[row] - 0.5f * cov_val;       // GAMMA = 1
      float pref = jax_uniform_key42(row);
      combined[row] = 0.5f * mv + 0.5f * pref;        // LAM = 0.5
    }
  } else if (bid < GRU_BLOCKS) {
    // ======== GRU (chunk-staged: 3 chunks of <=66x193 floats) ========
    float* T  = S;
    float* BI = S + 12738;
    float* BH = S + 12930;
    const int rowbase = bid * 16 + wid * 4;

    if (tid < 192) { BI[tid] = b_ih[tid]; BH[tid] = b_hh[tid]; }

    float u_d[4], v_d[4], h_d[4], dt[4], ef[4];
    int bb[4];
    #pragma unroll
    for (int rr = 0; rr < 4; ++rr) {
      int b = rowbase + rr; bb[rr] = b;
      int uu = u[b], vv = v[b];
      u_d[rr] = user_emb[uu*64 + lane];
      v_d[rr] = item_emb[vv*64 + lane];
      h_d[rr] = mem[uu*64 + lane];
      dt[rr]  = delta_t[b];
      ef[rr]  = edge_feat[b];
    }

    // ---- chunk 0: W_ih cols 0..63 (u_emb) ----
    for (int idx = tid; idx < 64*192; idx += 256) {
      int o = idx >> 6, j = idx & 63;
      T[j*193 + o] = w_ih[o*130 + j];
    }
    __syncthreads();

    float biR = BI[lane], biZ = BI[64+lane], biN = BI[128+lane];
    float bhR = BH[lane], bhZ = BH[64+lane], bhN = BH[128+lane];
    float accR[4], accZ[4], accN[4], hN[4];
    #pragma unroll
    for (int rr = 0; rr < 4; ++rr) { accR[rr]=biR+bhR; accZ[rr]=biZ+bhZ; accN[rr]=biN; hN[rr]=bhN; }

    for (int j = 0; j < 64; ++j) {
      float wR = T[j*193 + lane], wZ = T[j*193 + 64 + lane], wN = T[j*193 + 128 + lane];
      #pragma unroll
      for (int rr = 0; rr < 4; ++rr) {
        float m = __shfl(u_d[rr], j);
        accR[rr] = fmaf(wR, m, accR[rr]); accZ[rr] = fmaf(wZ, m, accZ[rr]); accN[rr] = fmaf(wN, m, accN[rr]);
      }
    }
    __syncthreads();

    // ---- chunk 1: W_ih cols 64..127 (v_emb) ----
    for (int idx = tid; idx < 64*192; idx += 256) {
      int o = idx >> 6, j = idx & 63;
      T[j*193 + o] = w_ih[o*130 + 64 + j];
    }
    __syncthreads();
    for (int j = 0; j < 64; ++j) {
      float wR = T[j*193 + lane], wZ = T[j*193 + 64 + lane], wN = T[j*193 + 128 + lane];
      #pragma unroll
      for (int rr = 0; rr < 4; ++rr) {
        float m = __shfl(v_d[rr], j);
        accR[rr] = fmaf(wR, m, accR[rr]); accZ[rr] = fmaf(wZ, m, accZ[rr]); accN[rr] = fmaf(wN, m, accN[rr]);
      }
    }
    __syncthreads();

    // ---- chunk 2: W_ih cols 128,129 (dt, ef) + W_hh (h) ----
    for (int idx = tid; idx < 384; idx += 256) {
      int o = idx >> 1, c = idx & 1;
      T[c*193 + o] = w_ih[o*130 + 128 + c];
    }
    for (int idx = tid; idx < 64*192; idx += 256) {
      int o = idx >> 6, jj = idx & 63;
      T[(2+jj)*193 + o] = w_hh[idx];
    }
    __syncthreads();
    {
      float wR = T[lane], wZ = T[64 + lane], wN = T[128 + lane];
      float eR = T[193 + lane], eZ = T[193 + 64 + lane], eN = T[193 + 128 + lane];
      #pragma unroll
      for (int rr = 0; rr < 4; ++rr) {
        accR[rr] = fmaf(wR, dt[rr], accR[rr]); accZ[rr] = fmaf(wZ, dt[rr], accZ[rr]); accN[rr] = fmaf(wN, dt[rr], accN[rr]);
        accR[rr] = fmaf(eR, ef[rr], accR[rr]); accZ[rr] = fmaf(eZ, ef[rr], accZ[rr]); accN[rr] = fmaf(eN, ef[rr], accN[rr]);
      }
    }
    for (int jj = 0; jj < 64; ++jj) {
      int base = (2+jj)*193;
      float wR = T[base + lane], wZ = T[base + 64 + lane], wN = T[base + 128 + lane];
      #pragma unroll
      for (int rr = 0; rr < 4; ++rr) {
        float m = __shfl(h_d[rr], jj);
        accR[rr] = fmaf(wR, m, accR[rr]); accZ[rr] = fmaf(wZ, m, accZ[rr]); hN[rr] = fmaf(wN, m, hN[rr]);
      }
    }

    #pragma unroll
    for (int rr = 0; rr < 4; ++rr) {
      float r = 1.0f / (1.0f + expf(-accR[rr]));
      float z = 1.0f / (1.0f + expf(-accZ[rr]));
      float n = tanhf(accN[rr] + r * hN[rr]);
      float hn = (1.0f - z) * n + z * h_d[rr];
      h_new_out[bb[rr]*64 + lane] = hn;
    }
  } else {
    // ======== attn (per-gate chunk staging) ========
    float* C    = S;
    float* OT   = S + 4160;
    float* BIN  = S + 8320;
    float* BOUT = S + 8512;
    const int abid = bid - GRU_BLOCKS;
    const int rowbase = abid * 8 + wid * 2;

    for (int idx = tid; idx < 64*64; idx += 256) {
      int k = idx >> 6, j = idx & 63;
      OT[j*65 + k] = out_w[idx];
    }
    if (tid < 192) BIN[tid] = in_b[tid];
    if (tid < 64)  BOUT[tid] = out_b[tid];

    float u_d[2], x1_d[2];
    int bb[2];
    #pragma unroll
    for (int rr = 0; rr < 2; ++rr) {
      int b = rowbase + rr; bb[rr] = b;
      int uu = u[b], vv = v[b];
      float ef = edge_feat[b];
      u_d[rr]  = user_emb[uu*64 + lane];
      x1_d[rr] = item_emb[vv*64 + lane] + ef;
    }

    float q0[2], k0[2], k1[2], v0[2], v1[2];

    // gate 0: q (token 0 only)
    for (int idx = tid; idx < 4096; idx += 256) {
      int o = idx >> 6, j = idx & 63;
      C[j*65 + o] = in_w[o*64 + j];
    }
    __syncthreads();
    {
      float bq = BIN[lane];
      #pragma unroll
      for (int rr = 0; rr < 2; ++rr) q0[rr] = bq;
      for (int j = 0; j < 64; ++j) {
        float wq = C[j*65 + lane];
        #pragma unroll
        for (int rr = 0; rr < 2; ++rr) q0[rr] = fmaf(wq, __shfl(u_d[rr], j), q0[rr]);
      }
    }
    __syncthreads();

    // gate 1: k (both tokens)
    for (int idx = tid; idx < 4096; idx += 256) {
      int o = idx >> 6, j = idx & 63;
      C[j*65 + o] = in_w[(64+o)*64 + j];
    }
    __syncthreads();
    {
      float bk = BIN[64+lane];
      #pragma unroll
      for (int rr = 0; rr < 2; ++rr) { k0[rr] = bk; k1[rr] = bk; }
      for (int j = 0; j < 64; ++j) {
        float wk = C[j*65 + lane];
        #pragma unroll
        for (int rr = 0; rr < 2; ++rr) {
          k0[rr] = fmaf(wk, __shfl(u_d[rr], j),  k0[rr]);
          k1[rr] = fmaf(wk, __shfl(x1_d[rr], j), k1[rr]);
        }
      }
    }
    __syncthreads();

    // gate 2: v (both tokens)
    for (int idx = tid; idx < 4096; idx += 256) {
      int o = idx >> 6, j = idx & 63;
      C[j*65 + o] = in_w[(128+o)*64 + j];
    }
    __syncthreads();
    {
      float bv = BIN[128+lane];
      #pragma unroll
      for (int rr = 0; rr < 2; ++rr) { v0[rr] = bv; v1[rr] = bv; }
      for (int j = 0; j < 64; ++j) {
        float wv = C[j*65 + lane];
        #pragma unroll
        for (int rr = 0; rr < 2; ++rr) {
          v0[rr] = fmaf(wv, __shfl(u_d[rr], j),  v0[rr]);
          v1[rr] = fmaf(wv, __shfl(x1_d[rr], j), v1[rr]);
        }
      }
    }

    #pragma unroll
    for (int rr = 0; rr < 2; ++rr) {
      float p0 = q0[rr]*k0[rr], p1 = q0[rr]*k1[rr];
      #pragma unroll
      for (int off = 1; off < 16; off <<= 1) { p0 += __shfl_xor(p0, off); p1 += __shfl_xor(p1, off); }
      float s0 = p0 * 0.25f, s1 = p1 * 0.25f;
      float m  = fmaxf(s0, s1);
      float e0 = expf(s0 - m), e1 = expf(s1 - m);
      float inv = 1.0f / (e0 + e1);
      float o_d = (e0 * v0[rr] + e1 * v1[rr]) * inv;
      float zacc = BOUT[lane];
      for (int j = 0; j < 64; ++j)
        zacc = fmaf(OT[j*65 + lane], __shfl(o_d, j), zacc);
      z_out[bb[rr]*64 + lane] = zacc;
    }
  }
}

// ---------------- top-5 helpers ----------------
__device__ inline u64 shfl_down_u64(u64 x, int off){
  unsigned lo = (unsigned)(x & 0xFFFFFFFFull), hi = (unsigned)(x >> 32);
  lo = __shfl_down(lo, off); hi = __shfl_down(hi, off);
  return ((u64)hi << 32) | (u64)lo;
}

__device__ inline u64 make_key(float val, int i){
  unsigned u = __float_as_uint(val);
  u ^= (u >> 31) ? 0xFFFFFFFFu : 0x80000000u;       // order-preserving float->uint
  return ((u64)u << 32) | (u64)(0xFFFFFFFFu - (unsigned)i); // tie: lower idx wins
}

// ---------------- kernel 2a: per-slice top-5 (40 blocks, 250 items each) ----------------
__global__ __launch_bounds__(256) void top5_stage1(
    const float* __restrict__ combined, u64* __restrict__ keys_out)
{
  __shared__ u64 redL[4];
  __shared__ u64 sel;
  const int tid = threadIdx.x, lane = tid & 63, wid = tid >> 6;
  const int i = blockIdx.x * 250 + tid;

  u64 key = 0ull;
  if (tid < 250 && i < NI_) key = make_key(combined[i], i);

  for (int r = 0; r < 5; ++r) {
    u64 best = key;
    #pragma unroll
    for (int off = 32; off > 0; off >>= 1) {
      u64 o = shfl_down_u64(best, off);
      if (o > best) best = o;
    }
    if (lane == 0) redL[wid] = best;
    __syncthreads();
    if (tid == 0) {
      u64 b = redL[0];
      for (int wv = 1; wv < 4; ++wv) if (redL[wv] > b) b = redL[wv];
      sel = b;
      keys_out[blockIdx.x * 5 + r] = b;
    }
    __syncthreads();
    if (key == sel) key = 0ull;
  }
}

// ---------------- kernel 2b: 16 blocks; each reduces 200 keys + emits 256 rows ----------------
__global__ __launch_bounds__(256) void top5_stage2(
    const u64* __restrict__ keys_in, const int* __restrict__ v,
    float* __restrict__ pos_out, float* __restrict__ neg_out)
{
  __shared__ u64 redL[4];
  __shared__ u64 sel;
  __shared__ int chosen[5];
  const int tid = threadIdx.x, lane = tid & 63, wid = tid >> 6;

  u64 key = (tid < 5 * S1_BLOCKS) ? keys_in[tid] : 0ull;

  for (int r = 0; r < 5; ++r) {
    u64 best = key;
    #pragma unroll
    for (int off = 32; off > 0; off >>= 1) {
      u64 o = shfl_down_u64(best, off);
      if (o > best) best = o;
    }
    if (lane == 0) redL[wid] = best;
    __syncthreads();
    if (tid == 0) {
      u64 b = redL[0];
      for (int wv = 1; wv < 4; ++wv) if (redL[wv] > b) b = redL[wv];
      sel = b;
      chosen[r] = (int)(0xFFFFFFFFu - (unsigned)(b & 0xFFFFFFFFull));
    }
    __syncthreads();
    if (key == sel) key = 0ull;
  }

  const int b = blockIdx.x * 256 + tid;   // 16 blocks x 256 = 4096 rows
  int vb = v[b];
  int f[4]; int n = 0;
  #pragma unroll
  for (int c = 0; c < 5; ++c) { if (n < 4 && chosen[c] != vb) f[n++] = chosen[c]; }
  pos_out[b]       = (float)f[0];
  neg_out[b*3 + 0] = (float)f[1];
  neg_out[b*3 + 1] = (float)f[2];
  neg_out[b*3 + 2] = (float)f[3];
}

// ---------------- launch ----------------
extern "C" void kernel_launch(void* const* d_in, const int* in_sizes, int n_in,
                              void* d_out, int out_size, void* d_ws, size_t ws_size,
                              hipStream_t stream)
{
  const int*   u        = (const int*)d_in[0];
  const int*   v        = (const int*)d_in[1];
  /* t = d_in[2] unused */
  const float* delta_t  = (const float*)d_in[3];
  const float* edge_f   = (const float*)d_in[4];
  const float* returns  = (const float*)d_in[5];
  const float* cov      = (const float*)d_in[6];
  const float* user_emb = (const float*)d_in[7];
  const float* item_emb = (const float*)d_in[8];
  const float* mem      = (const float*)d_in[9];
  const float* w_ih     = (const float*)d_in[10];
  const float* w_hh     = (const float*)d_in[11];
  const float* b_ih     = (const float*)d_in[12];
  const float* b_hh     = (const float*)d_in[13];
  const float* in_w     = (const float*)d_in[14];
  const float* in_b     = (const float*)d_in[15];
  const float* out_w    = (const float*)d_in[16];
  const float* out_b    = (const float*)d_in[17];

  float* out     = (float*)d_out;
  float* z_out   = out;                    // B*D
  float* h_out   = out + BB_*DD_;          // B*D
  float* pos_out = out + 2*BB_*DD_;        // B
  float* neg_out = out + 2*BB_*DD_ + BB_;  // B*3

  float* ws        = (float*)d_ws;
  float* w_hist    = ws;                   // NI_ floats (16B-aligned)
  float* combined  = ws + 10240;           // NI_ floats
  u64*   keys      = (u64*)(ws + 20480);   // S1_BLOCKS*5 u64

  hipMemsetAsync(w_hist, 0, NI_ * sizeof(float), stream);
  hipLaunchKernelGGL(hist_kernel, dim3(16), dim3(256), 0, stream, v, w_hist);
  hipLaunchKernelGGL(big_kernel, dim3(BIG_BLOCKS), dim3(256), 0, stream,
                     u, v, delta_t, edge_f, w_hist, returns, cov, combined,
                     user_emb, item_emb, mem, w_ih, w_hh, b_ih, b_hh,
                     in_w, in_b, out_w, out_b, h_out, z_out);
  hipLaunchKernelGGL(top5_stage1, dim3(S1_BLOCKS), dim3(256), 0, stream,
                     combined, keys);
  hipLaunchKernelGGL(top5_stage2, dim3(16), dim3(256), 0, stream,
                     keys, v, pos_out, neg_out);
}